// Round 2
// baseline (250.050 us; speedup 1.0000x reference)
//
#include <hip/hip_runtime.h>
#include <hip/hip_fp16.h>

#define NMESH 128
#define NMESH2 (128 * 128)
#define NMESH3 (128 * 128 * 128)
#define NPOINTS 100000
#define NCH 16

// ---------------------------------------------------------------------------
// Kernel 1 (REWRITTEN): transpose (C,X,Y,Z) fp32 -> (X,Y,Z,C) fp16.
// Each thread owns 4 consecutive spatial cells:
//   reads  16x float4  (dwordx4, 16 B/lane, perfectly coalesced per c-plane)
//   writes  8x uint4   (dwordx4, 16 B/lane, 128 B thread stride)
// No LDS, no barrier. 2048 blocks x 256 threads. 192 MiB total traffic.
// ---------------------------------------------------------------------------
__device__ __forceinline__ float f4comp(const float4& v, int j) {
    // j is always a compile-time constant after unrolling -> folds to a reg.
    switch (j) {
        case 0:  return v.x;
        case 1:  return v.y;
        case 2:  return v.z;
        default: return v.w;
    }
}

__global__ __launch_bounds__(256) void transpose_to_half_v2(
    const float* __restrict__ in,   // [16][2M]
    __half* __restrict__ outT)      // [2M][16]
{
    const int tid = blockIdx.x * 256 + threadIdx.x;   // 0 .. NMESH3/4 - 1
    const size_t s0 = (size_t)tid * 4;                // first of 4 cells

    float4 v[NCH];
#pragma unroll
    for (int c = 0; c < NCH; ++c) {
        v[c] = *(const float4*)(in + (size_t)c * NMESH3 + s0);
    }

    uint4* o = (uint4*)(outT + s0 * NCH);  // 4 cells * 32 B = 8 uint4
#pragma unroll
    for (int j = 0; j < 4; ++j) {          // cell within the quad
        uint32_t w[8];
#pragma unroll
        for (int cp = 0; cp < 8; ++cp) {   // channel pair
            const float f0 = f4comp(v[2 * cp + 0], j);
            const float f1 = f4comp(v[2 * cp + 1], j);
            w[cp] = (uint32_t)__half_as_ushort(__float2half(f0)) |
                    ((uint32_t)__half_as_ushort(__float2half(f1)) << 16);
        }
        o[2 * j + 0] = make_uint4(w[0], w[1], w[2], w[3]);
        o[2 * j + 1] = make_uint4(w[4], w[5], w[6], w[7]);
    }
}

// ---------------------------------------------------------------------------
// Kernel 2 (unchanged from round 1 -- attribution): gather from transposed
// fp16 mesh. 4 lanes per point, lane owns channel quad; 8 B dwordx2 per tap;
// coalesced float4 output store.
// ---------------------------------------------------------------------------
__global__ __launch_bounds__(256) void gather_half_quad_kernel(
    const __half* __restrict__ meshT,  // [2M][16]
    const float* __restrict__ pts,     // [100000][3]
    float4* __restrict__ out)          // [100000][4] of float4
{
    const int tid = blockIdx.x * 256 + threadIdx.x;
    const int q = tid & 3;   // channel quad
    const int p = tid >> 2;  // point
    if (p >= NPOINTS) return;

    const float SP = 0.1f;
    const float pcx = pts[p * 3 + 0] / SP;
    const float pcy = pts[p * 3 + 1] / SP;
    const float pcz = pts[p * 3 + 2] / SP;

    const int rx = (int)rintf(pcx);
    const int ry = (int)rintf(pcy);
    const int rz = (int)rintf(pcz);

    const float dx = pcx - (float)rx;
    const float dy = pcy - (float)ry;
    const float dz = pcz - (float)rz;

    float wX[3], wY[3], wZ[3];
    wX[0] = (2.0f * dx - 1.0f) * (2.0f * dx - 1.0f) * 0.125f;
    wX[1] = 0.75f - dx * dx;
    wX[2] = (2.0f * dx + 1.0f) * (2.0f * dx + 1.0f) * 0.125f;
    wY[0] = (2.0f * dy - 1.0f) * (2.0f * dy - 1.0f) * 0.125f;
    wY[1] = 0.75f - dy * dy;
    wY[2] = (2.0f * dy + 1.0f) * (2.0f * dy + 1.0f) * 0.125f;
    wZ[0] = (2.0f * dz - 1.0f) * (2.0f * dz - 1.0f) * 0.125f;
    wZ[1] = 0.75f - dz * dz;
    wZ[2] = (2.0f * dz + 1.0f) * (2.0f * dz + 1.0f) * 0.125f;

    int xo[3], yo[3], zq[3];
#pragma unroll
    for (int k = 0; k < 3; ++k) {
        xo[k] = ((rx - 1 + k) & (NMESH - 1)) * (NMESH2 * NCH);
        yo[k] = ((ry - 1 + k) & (NMESH - 1)) * (NMESH * NCH);
        zq[k] = ((rz - 1 + k) & (NMESH - 1)) * NCH + q * 4;
    }

    float4 acc = make_float4(0.0f, 0.0f, 0.0f, 0.0f);
#pragma unroll
    for (int a = 0; a < 3; ++a) {
#pragma unroll
        for (int b = 0; b < 3; ++b) {
            const __half* __restrict__ base = meshT + xo[a] + yo[b];
            const float wxy = wX[a] * wY[b];
#pragma unroll
            for (int k = 0; k < 3; ++k) {
                union { uint2 u; __half2 h[2]; } d;
                d.u = *(const uint2*)(base + zq[k]);
                const float2 f01 = __half22float2(d.h[0]);
                const float2 f23 = __half22float2(d.h[1]);
                const float w = wxy * wZ[k];
                acc.x = fmaf(f01.x, w, acc.x);
                acc.y = fmaf(f01.y, w, acc.y);
                acc.z = fmaf(f23.x, w, acc.z);
                acc.w = fmaf(f23.y, w, acc.w);
            }
        }
    }

    out[tid] = acc;
}

// ---------------------------------------------------------------------------
// Fallback in case ws_size is too small for the fp16 mesh.
// ---------------------------------------------------------------------------
__global__ __launch_bounds__(256) void mesh_interp_fallback_kernel(
    const float* __restrict__ mesh,
    const float* __restrict__ pts,
    float* __restrict__ out)
{
    const int tid = blockIdx.x * 256 + threadIdx.x;
    const int c = tid & (NCH - 1);
    const int p = tid >> 4;
    if (p >= NPOINTS) return;

    const float SP = 0.1f;
    const float pcx = pts[p * 3 + 0] / SP;
    const float pcy = pts[p * 3 + 1] / SP;
    const float pcz = pts[p * 3 + 2] / SP;

    const int rx = (int)rintf(pcx);
    const int ry = (int)rintf(pcy);
    const int rz = (int)rintf(pcz);

    const float dx = pcx - (float)rx;
    const float dy = pcy - (float)ry;
    const float dz = pcz - (float)rz;

    float wX[3], wY[3], wZ[3];
    wX[0] = (2.0f * dx - 1.0f) * (2.0f * dx - 1.0f) * 0.125f;
    wX[1] = 0.75f - dx * dx;
    wX[2] = (2.0f * dx + 1.0f) * (2.0f * dx + 1.0f) * 0.125f;
    wY[0] = (2.0f * dy - 1.0f) * (2.0f * dy - 1.0f) * 0.125f;
    wY[1] = 0.75f - dy * dy;
    wY[2] = (2.0f * dy + 1.0f) * (2.0f * dy + 1.0f) * 0.125f;
    wZ[0] = (2.0f * dz - 1.0f) * (2.0f * dz - 1.0f) * 0.125f;
    wZ[1] = 0.75f - dz * dz;
    wZ[2] = (2.0f * dz + 1.0f) * (2.0f * dz + 1.0f) * 0.125f;

    int xb[3], yb[3], zi[3];
#pragma unroll
    for (int k = 0; k < 3; ++k) {
        xb[k] = ((rx - 1 + k) & (NMESH - 1)) * NMESH2;
        yb[k] = ((ry - 1 + k) & (NMESH - 1)) * NMESH;
        zi[k] = ((rz - 1 + k) & (NMESH - 1));
    }

    const float* __restrict__ mc = mesh + (size_t)c * NMESH3;
    float acc = 0.0f;
#pragma unroll
    for (int a = 0; a < 3; ++a) {
#pragma unroll
        for (int b = 0; b < 3; ++b) {
            const float* __restrict__ row = mc + xb[a] + yb[b];
            const float wxy = wX[a] * wY[b];
            acc = fmaf(row[zi[0]], wxy * wZ[0], acc);
            acc = fmaf(row[zi[1]], wxy * wZ[1], acc);
            acc = fmaf(row[zi[2]], wxy * wZ[2], acc);
        }
    }
    out[tid] = acc;
}

extern "C" void kernel_launch(void* const* d_in, const int* in_sizes, int n_in,
                              void* d_out, int out_size, void* d_ws, size_t ws_size,
                              hipStream_t stream) {
    const float* mesh = (const float*)d_in[0];
    const float* pts  = (const float*)d_in[1];

    const size_t needed = (size_t)NMESH3 * NCH * sizeof(__half);  // 64 MiB

    if (ws_size >= needed) {
        __half* meshT = (__half*)d_ws;
        transpose_to_half_v2<<<NMESH3 / 4 / 256, 256, 0, stream>>>(mesh, meshT);
        const int total = NPOINTS * 4;  // 4 lanes per point (channel quads)
        gather_half_quad_kernel<<<(total + 255) / 256, 256, 0, stream>>>(
            meshT, pts, (float4*)d_out);
    } else {
        const int total = NPOINTS * NCH;
        mesh_interp_fallback_kernel<<<(total + 255) / 256, 256, 0, stream>>>(
            mesh, pts, (float*)d_out);
    }
}

// Round 3
// 226.759 us; speedup vs baseline: 1.1027x; 1.1027x over previous
//
#include <hip/hip_runtime.h>
#include <hip/hip_fp16.h>

#define NMESH 128
#define NMESH2 (128 * 128)
#define NMESH3 (128 * 128 * 128)
#define NPOINTS 100000
#define NCH 16

// ---------------------------------------------------------------------------
// Kernel 1 (v3): transpose (C,X,Y,Z) fp32 -> (X,Y,Z,C) fp16 via LDS bounce.
// Tile = 256 consecutive cells per block (8192 blocks x 256 threads).
//   Read : per wave one channel's 1 KB contiguous (float4, 16 B/lane)
//   Stage: ds_write_b128 into channel-major fp32 tile lds[c][256]
//   Out  : per thread, 8 channels of one cell-half via conflict-free
//          ds_read_b32 (2 lanes/bank = free), pack RNE fp16, uint4 store --
//          lanes cover 1 KB contiguous output per instruction.
// Both global sides are 16 B/lane fully coalesced; no strided access.
// ---------------------------------------------------------------------------
__global__ __launch_bounds__(256) void transpose_to_half_v3(
    const float* __restrict__ in,   // [16][2M]
    __half* __restrict__ outT)      // [2M][16]
{
    __shared__ float lds[NCH * 256];   // 16 KB, channel-major [c][s]
    const int t = threadIdx.x;
    const int s_base = blockIdx.x * 256;
    const int f = t & 63;      // float4 index within a channel row
    const int c0 = t >> 6;     // 0..3

    // Read phase: iteration k, wave w handles channel c0 + 4k.
#pragma unroll
    for (int k = 0; k < 4; ++k) {
        const int c = c0 + 4 * k;
        const float4 v = *(const float4*)(in + (size_t)c * NMESH3 + s_base + 4 * f);
        *(float4*)&lds[c * 256 + 4 * f] = v;   // ds_write_b128, 16B-aligned
    }
    __syncthreads();

    // Write phase: uint4 i covers cell s = i>>1, channels h..h+7 (h = (i&1)*8).
    uint4* o = (uint4*)(outT + (size_t)s_base * NCH);  // 512 uint4 per tile
#pragma unroll
    for (int r = 0; r < 2; ++r) {
        const int i = t + 256 * r;
        const int s = i >> 1;
        const int h = (i & 1) * 8;
        uint32_t w[4];
#pragma unroll
        for (int m = 0; m < 4; ++m) {
            const float f0 = lds[(h + 2 * m + 0) * 256 + s];
            const float f1 = lds[(h + 2 * m + 1) * 256 + s];
            w[m] = (uint32_t)__half_as_ushort(__float2half(f0)) |
                   ((uint32_t)__half_as_ushort(__float2half(f1)) << 16);
        }
        o[i] = make_uint4(w[0], w[1], w[2], w[3]);
    }
}

// ---------------------------------------------------------------------------
// Kernel 2 (unchanged -- attribution): gather from transposed fp16 mesh.
// 4 lanes per point, lane owns channel quad; 8 B dwordx2 per tap;
// coalesced float4 output store.
// ---------------------------------------------------------------------------
__global__ __launch_bounds__(256) void gather_half_quad_kernel(
    const __half* __restrict__ meshT,  // [2M][16]
    const float* __restrict__ pts,     // [100000][3]
    float4* __restrict__ out)          // [100000][4] of float4
{
    const int tid = blockIdx.x * 256 + threadIdx.x;
    const int q = tid & 3;   // channel quad
    const int p = tid >> 2;  // point
    if (p >= NPOINTS) return;

    const float SP = 0.1f;
    const float pcx = pts[p * 3 + 0] / SP;
    const float pcy = pts[p * 3 + 1] / SP;
    const float pcz = pts[p * 3 + 2] / SP;

    const int rx = (int)rintf(pcx);
    const int ry = (int)rintf(pcy);
    const int rz = (int)rintf(pcz);

    const float dx = pcx - (float)rx;
    const float dy = pcy - (float)ry;
    const float dz = pcz - (float)rz;

    float wX[3], wY[3], wZ[3];
    wX[0] = (2.0f * dx - 1.0f) * (2.0f * dx - 1.0f) * 0.125f;
    wX[1] = 0.75f - dx * dx;
    wX[2] = (2.0f * dx + 1.0f) * (2.0f * dx + 1.0f) * 0.125f;
    wY[0] = (2.0f * dy - 1.0f) * (2.0f * dy - 1.0f) * 0.125f;
    wY[1] = 0.75f - dy * dy;
    wY[2] = (2.0f * dy + 1.0f) * (2.0f * dy + 1.0f) * 0.125f;
    wZ[0] = (2.0f * dz - 1.0f) * (2.0f * dz - 1.0f) * 0.125f;
    wZ[1] = 0.75f - dz * dz;
    wZ[2] = (2.0f * dz + 1.0f) * (2.0f * dz + 1.0f) * 0.125f;

    int xo[3], yo[3], zq[3];
#pragma unroll
    for (int k = 0; k < 3; ++k) {
        xo[k] = ((rx - 1 + k) & (NMESH - 1)) * (NMESH2 * NCH);
        yo[k] = ((ry - 1 + k) & (NMESH - 1)) * (NMESH * NCH);
        zq[k] = ((rz - 1 + k) & (NMESH - 1)) * NCH + q * 4;
    }

    float4 acc = make_float4(0.0f, 0.0f, 0.0f, 0.0f);
#pragma unroll
    for (int a = 0; a < 3; ++a) {
#pragma unroll
        for (int b = 0; b < 3; ++b) {
            const __half* __restrict__ base = meshT + xo[a] + yo[b];
            const float wxy = wX[a] * wY[b];
#pragma unroll
            for (int k = 0; k < 3; ++k) {
                union { uint2 u; __half2 h[2]; } d;
                d.u = *(const uint2*)(base + zq[k]);
                const float2 f01 = __half22float2(d.h[0]);
                const float2 f23 = __half22float2(d.h[1]);
                const float w = wxy * wZ[k];
                acc.x = fmaf(f01.x, w, acc.x);
                acc.y = fmaf(f01.y, w, acc.y);
                acc.z = fmaf(f23.x, w, acc.z);
                acc.w = fmaf(f23.y, w, acc.w);
            }
        }
    }

    out[tid] = acc;
}

// ---------------------------------------------------------------------------
// Fallback in case ws_size is too small for the fp16 mesh.
// ---------------------------------------------------------------------------
__global__ __launch_bounds__(256) void mesh_interp_fallback_kernel(
    const float* __restrict__ mesh,
    const float* __restrict__ pts,
    float* __restrict__ out)
{
    const int tid = blockIdx.x * 256 + threadIdx.x;
    const int c = tid & (NCH - 1);
    const int p = tid >> 4;
    if (p >= NPOINTS) return;

    const float SP = 0.1f;
    const float pcx = pts[p * 3 + 0] / SP;
    const float pcy = pts[p * 3 + 1] / SP;
    const float pcz = pts[p * 3 + 2] / SP;

    const int rx = (int)rintf(pcx);
    const int ry = (int)rintf(pcy);
    const int rz = (int)rintf(pcz);

    const float dx = pcx - (float)rx;
    const float dy = pcy - (float)ry;
    const float dz = pcz - (float)rz;

    float wX[3], wY[3], wZ[3];
    wX[0] = (2.0f * dx - 1.0f) * (2.0f * dx - 1.0f) * 0.125f;
    wX[1] = 0.75f - dx * dx;
    wX[2] = (2.0f * dx + 1.0f) * (2.0f * dx + 1.0f) * 0.125f;
    wY[0] = (2.0f * dy - 1.0f) * (2.0f * dy - 1.0f) * 0.125f;
    wY[1] = 0.75f - dy * dy;
    wY[2] = (2.0f * dy + 1.0f) * (2.0f * dy + 1.0f) * 0.125f;
    wZ[0] = (2.0f * dz - 1.0f) * (2.0f * dz - 1.0f) * 0.125f;
    wZ[1] = 0.75f - dz * dz;
    wZ[2] = (2.0f * dz + 1.0f) * (2.0f * dz + 1.0f) * 0.125f;

    int xb[3], yb[3], zi[3];
#pragma unroll
    for (int k = 0; k < 3; ++k) {
        xb[k] = ((rx - 1 + k) & (NMESH - 1)) * NMESH2;
        yb[k] = ((ry - 1 + k) & (NMESH - 1)) * NMESH;
        zi[k] = ((rz - 1 + k) & (NMESH - 1));
    }

    const float* __restrict__ mc = mesh + (size_t)c * NMESH3;
    float acc = 0.0f;
#pragma unroll
    for (int a = 0; a < 3; ++a) {
#pragma unroll
        for (int b = 0; b < 3; ++b) {
            const float* __restrict__ row = mc + xb[a] + yb[b];
            const float wxy = wX[a] * wY[b];
            acc = fmaf(row[zi[0]], wxy * wZ[0], acc);
            acc = fmaf(row[zi[1]], wxy * wZ[1], acc);
            acc = fmaf(row[zi[2]], wxy * wZ[2], acc);
        }
    }
    out[tid] = acc;
}

extern "C" void kernel_launch(void* const* d_in, const int* in_sizes, int n_in,
                              void* d_out, int out_size, void* d_ws, size_t ws_size,
                              hipStream_t stream) {
    const float* mesh = (const float*)d_in[0];
    const float* pts  = (const float*)d_in[1];

    const size_t needed = (size_t)NMESH3 * NCH * sizeof(__half);  // 64 MiB

    if (ws_size >= needed) {
        __half* meshT = (__half*)d_ws;
        transpose_to_half_v3<<<NMESH3 / 256, 256, 0, stream>>>(mesh, meshT);
        const int total = NPOINTS * 4;  // 4 lanes per point (channel quads)
        gather_half_quad_kernel<<<(total + 255) / 256, 256, 0, stream>>>(
            meshT, pts, (float4*)d_out);
    } else {
        const int total = NPOINTS * NCH;
        mesh_interp_fallback_kernel<<<(total + 255) / 256, 256, 0, stream>>>(
            mesh, pts, (float*)d_out);
    }
}

// Round 5
// 226.632 us; speedup vs baseline: 1.1033x; 1.0006x over previous
//
#include <hip/hip_runtime.h>
#include <hip/hip_fp16.h>

#define NMESH 128
#define NMESH2 (128 * 128)
#define NMESH3 (128 * 128 * 128)
#define NPOINTS 100000
#define NCH 16

// ---------------------------------------------------------------------------
// Kernel 1 (v4): transpose (C,X,Y,Z) fp32 -> (X,Y,Z,C) fp16.
// Persistent grid (2048 blocks), grid-stride over 8192 tiles of 256 cells.
//   - double-buffered 16KB LDS tiles: ONE barrier per tile; stores of tile i
//     overlap loads of tile i+1.
//   - per-tile channel rotation decorrelates the 16 reads at 64MiB stride
//     (power-of-2 HBM channel aliasing) across concurrent blocks.
//   - both global sides 16 B/lane fully coalesced (float4 in, uint4 out).
// ---------------------------------------------------------------------------
__global__ __launch_bounds__(256) void transpose_to_half_v4(
    const float* __restrict__ in,   // [16][2M]
    __half* __restrict__ outT)      // [2M][16]
{
    __shared__ float lds[2][NCH * 256];   // 2 x 16 KB
    const int t = threadIdx.x;
    const int f = t & 63;      // float4 index within a channel row
    const int c0 = t >> 6;     // wave id 0..3
    const int nTiles = NMESH3 / 256;      // 8192

    int buf = 0;
    for (int tile = blockIdx.x; tile < nTiles; tile += gridDim.x, buf ^= 1) {
        const int s_base = tile * 256;

        // Load phase: 16 x 1KB contiguous reads, channel order rotated per tile.
#pragma unroll
        for (int k = 0; k < 4; ++k) {
            const int c = (c0 + 4 * k + tile) & 15;
            const float4 v =
                *(const float4*)(in + (size_t)c * NMESH3 + s_base + 4 * f);
            *(float4*)&lds[buf][c * 256 + 4 * f] = v;   // ds_write_b128
        }
        __syncthreads();   // single barrier per tile (dbuf makes this safe)

        // Store phase: uint4 i covers cell s=i>>1, channels h..h+7 (h=(i&1)*8).
        uint4* o = (uint4*)(outT + (size_t)s_base * NCH);  // 512 uint4 per tile
#pragma unroll
        for (int r = 0; r < 2; ++r) {
            const int i = t + 256 * r;
            const int s = i >> 1;
            const int h = (i & 1) * 8;
            uint32_t w[4];
#pragma unroll
            for (int m = 0; m < 4; ++m) {
                const float f0 = lds[buf][(h + 2 * m + 0) * 256 + s];
                const float f1 = lds[buf][(h + 2 * m + 1) * 256 + s];
                w[m] = (uint32_t)__half_as_ushort(__float2half(f0)) |
                       ((uint32_t)__half_as_ushort(__float2half(f1)) << 16);
            }
            o[i] = make_uint4(w[0], w[1], w[2], w[3]);
        }
        // no second barrier: next tile writes the OTHER buffer; a wave can only
        // reach tile i+2's load of this buffer after passing tile i+1's barrier,
        // which (by program order) requires all waves to have finished tile i's
        // store-phase reads. Safe.
    }
}

// ---------------------------------------------------------------------------
// Kernel 2 (unchanged -- attribution): gather from transposed fp16 mesh.
// 4 lanes per point, lane owns channel quad; 8 B dwordx2 per tap;
// coalesced float4 output store.
// ---------------------------------------------------------------------------
__global__ __launch_bounds__(256) void gather_half_quad_kernel(
    const __half* __restrict__ meshT,  // [2M][16]
    const float* __restrict__ pts,     // [100000][3]
    float4* __restrict__ out)          // [100000][4] of float4
{
    const int tid = blockIdx.x * 256 + threadIdx.x;
    const int q = tid & 3;   // channel quad
    const int p = tid >> 2;  // point
    if (p >= NPOINTS) return;

    const float SP = 0.1f;
    const float pcx = pts[p * 3 + 0] / SP;
    const float pcy = pts[p * 3 + 1] / SP;
    const float pcz = pts[p * 3 + 2] / SP;

    const int rx = (int)rintf(pcx);
    const int ry = (int)rintf(pcy);
    const int rz = (int)rintf(pcz);

    const float dx = pcx - (float)rx;
    const float dy = pcy - (float)ry;
    const float dz = pcz - (float)rz;

    float wX[3], wY[3], wZ[3];
    wX[0] = (2.0f * dx - 1.0f) * (2.0f * dx - 1.0f) * 0.125f;
    wX[1] = 0.75f - dx * dx;
    wX[2] = (2.0f * dx + 1.0f) * (2.0f * dx + 1.0f) * 0.125f;
    wY[0] = (2.0f * dy - 1.0f) * (2.0f * dy - 1.0f) * 0.125f;
    wY[1] = 0.75f - dy * dy;
    wY[2] = (2.0f * dy + 1.0f) * (2.0f * dy + 1.0f) * 0.125f;
    wZ[0] = (2.0f * dz - 1.0f) * (2.0f * dz - 1.0f) * 0.125f;
    wZ[1] = 0.75f - dz * dz;
    wZ[2] = (2.0f * dz + 1.0f) * (2.0f * dz + 1.0f) * 0.125f;

    int xo[3], yo[3], zq[3];
#pragma unroll
    for (int k = 0; k < 3; ++k) {
        xo[k] = ((rx - 1 + k) & (NMESH - 1)) * (NMESH2 * NCH);
        yo[k] = ((ry - 1 + k) & (NMESH - 1)) * (NMESH * NCH);
        zq[k] = ((rz - 1 + k) & (NMESH - 1)) * NCH + q * 4;
    }

    float4 acc = make_float4(0.0f, 0.0f, 0.0f, 0.0f);
#pragma unroll
    for (int a = 0; a < 3; ++a) {
#pragma unroll
        for (int b = 0; b < 3; ++b) {
            const __half* __restrict__ base = meshT + xo[a] + yo[b];
            const float wxy = wX[a] * wY[b];
#pragma unroll
            for (int k = 0; k < 3; ++k) {
                union { uint2 u; __half2 h[2]; } d;
                d.u = *(const uint2*)(base + zq[k]);
                const float2 f01 = __half22float2(d.h[0]);
                const float2 f23 = __half22float2(d.h[1]);
                const float w = wxy * wZ[k];
                acc.x = fmaf(f01.x, w, acc.x);
                acc.y = fmaf(f01.y, w, acc.y);
                acc.z = fmaf(f23.x, w, acc.z);
                acc.w = fmaf(f23.y, w, acc.w);
            }
        }
    }

    out[tid] = acc;
}

// ---------------------------------------------------------------------------
// Fallback in case ws_size is too small for the fp16 mesh.
// ---------------------------------------------------------------------------
__global__ __launch_bounds__(256) void mesh_interp_fallback_kernel(
    const float* __restrict__ mesh,
    const float* __restrict__ pts,
    float* __restrict__ out)
{
    const int tid = blockIdx.x * 256 + threadIdx.x;
    const int c = tid & (NCH - 1);
    const int p = tid >> 4;
    if (p >= NPOINTS) return;

    const float SP = 0.1f;
    const float pcx = pts[p * 3 + 0] / SP;
    const float pcy = pts[p * 3 + 1] / SP;
    const float pcz = pts[p * 3 + 2] / SP;

    const int rx = (int)rintf(pcx);
    const int ry = (int)rintf(pcy);
    const int rz = (int)rintf(pcz);

    const float dx = pcx - (float)rx;
    const float dy = pcy - (float)ry;
    const float dz = pcz - (float)rz;

    float wX[3], wY[3], wZ[3];
    wX[0] = (2.0f * dx - 1.0f) * (2.0f * dx - 1.0f) * 0.125f;
    wX[1] = 0.75f - dx * dx;
    wX[2] = (2.0f * dx + 1.0f) * (2.0f * dx + 1.0f) * 0.125f;
    wY[0] = (2.0f * dy - 1.0f) * (2.0f * dy - 1.0f) * 0.125f;
    wY[1] = 0.75f - dy * dy;
    wY[2] = (2.0f * dy + 1.0f) * (2.0f * dy + 1.0f) * 0.125f;
    wZ[0] = (2.0f * dz - 1.0f) * (2.0f * dz - 1.0f) * 0.125f;
    wZ[1] = 0.75f - dz * dz;
    wZ[2] = (2.0f * dz + 1.0f) * (2.0f * dz + 1.0f) * 0.125f;

    int xb[3], yb[3], zi[3];
#pragma unroll
    for (int k = 0; k < 3; ++k) {
        xb[k] = ((rx - 1 + k) & (NMESH - 1)) * NMESH2;
        yb[k] = ((ry - 1 + k) & (NMESH - 1)) * NMESH;
        zi[k] = ((rz - 1 + k) & (NMESH - 1));
    }

    const float* __restrict__ mc = mesh + (size_t)c * NMESH3;
    float acc = 0.0f;
#pragma unroll
    for (int a = 0; a < 3; ++a) {
#pragma unroll
        for (int b = 0; b < 3; ++b) {
            const float* __restrict__ row = mc + xb[a] + yb[b];
            const float wxy = wX[a] * wY[b];
            acc = fmaf(row[zi[0]], wxy * wZ[0], acc);
            acc = fmaf(row[zi[1]], wxy * wZ[1], acc);
            acc = fmaf(row[zi[2]], wxy * wZ[2], acc);
        }
    }
    out[tid] = acc;
}

extern "C" void kernel_launch(void* const* d_in, const int* in_sizes, int n_in,
                              void* d_out, int out_size, void* d_ws, size_t ws_size,
                              hipStream_t stream) {
    const float* mesh = (const float*)d_in[0];
    const float* pts  = (const float*)d_in[1];

    const size_t needed = (size_t)NMESH3 * NCH * sizeof(__half);  // 64 MiB

    if (ws_size >= needed) {
        __half* meshT = (__half*)d_ws;
        transpose_to_half_v4<<<2048, 256, 0, stream>>>(mesh, meshT);
        const int total = NPOINTS * 4;  // 4 lanes per point (channel quads)
        gather_half_quad_kernel<<<(total + 255) / 256, 256, 0, stream>>>(
            meshT, pts, (float4*)d_out);
    } else {
        const int total = NPOINTS * NCH;
        mesh_interp_fallback_kernel<<<(total + 255) / 256, 256, 0, stream>>>(
            mesh, pts, (float*)d_out);
    }
}